// Round 5
// baseline (1367.973 us; speedup 1.0000x reference)
//
#include <hip/hip_runtime.h>

// DoubleSin via bf16 MFMA (16x16x32), zero-LDS.
// Round-5 = round-4 with the occupancy fix ONLY:
//  - grid 512 -> 1024 blocks (4096 waves = 4 waves/SIMD at 128 VGPR; previously
//    2048 waves = 2/SIMD self-cap -> VALUBusy 52%, latency-bound)
//  - __launch_bounds__(256,4) pins the allocator at <=128 VGPR.
// Structure: D = W'.H (weights as A-operand); D registers of layer L are
// exactly the B fragment of layer L+1 (no cross-lane traffic). Snake scales
// folded into weights: W_L' = diag(a_L) W_L diag(1/a_{L-1}); activation is
// param-free g(q) = q + sin^2(q). 3-term bf16 split Wh*Bh + Wh*Bl + Wl*Bh.

typedef __attribute__((ext_vector_type(8))) short bf8v;
typedef __attribute__((ext_vector_type(4))) float f4v;

union BF8U { bf8v v; unsigned d[4]; unsigned short s[8]; };

__device__ __forceinline__ unsigned short f2bf(float f) {   // preamble only
    unsigned u = __builtin_bit_cast(unsigned, f);
    u += 0x7fffu + ((u >> 16) & 1u);
    return (unsigned short)(u >> 16);
}
__device__ __forceinline__ float bf2f(unsigned short b) {
    return __builtin_bit_cast(float, (unsigned)b << 16);
}
__device__ __forceinline__ unsigned cvt_pk_bf16(float lo, float hi) {
    unsigned r;
    asm("v_cvt_pk_bf16_f32 %0, %1, %2" : "=v"(r) : "v"(lo), "v"(hi));
    return r;
}

#define MFMA(a, b, c) __builtin_amdgcn_mfma_f32_16x16x32_bf16((a), (b), (c), 0, 0, 0)

// g(q) = q + sin^2 q on all 16 accs, then build hi/lo B fragments via cvt_pk
__device__ __forceinline__ void act_and_frags(f4v (&acc)[4], bf8v (&Bh)[2], bf8v (&Bl)[2]) {
    #pragma unroll
    for (int t = 0; t < 4; ++t) {
        #pragma unroll
        for (int j = 0; j < 4; ++j) {
            float q = acc[t][j];
            float s = __sinf(q);
            acc[t][j] = fmaf(s, s, q);
        }
    }
    #pragma unroll
    for (int s2 = 0; s2 < 2; ++s2) {
        BF8U h, l;
        #pragma unroll
        for (int p = 0; p < 4; ++p) {
            const int t = 2 * s2 + (p >> 1);
            const int j0 = (p & 1) * 2;
            const float v0 = acc[t][j0], v1 = acc[t][j0 + 1];
            const unsigned hd = cvt_pk_bf16(v0, v1);      // lo16=bf(v0), hi16=bf(v1)
            h.d[p] = hd;
            const float r0 = v0 - __builtin_bit_cast(float, hd << 16);
            const float r1 = v1 - __builtin_bit_cast(float, hd & 0xffff0000u);
            l.d[p] = cvt_pk_bf16(r0, r1);
        }
        Bh[s2] = h.v; Bl[s2] = l.v;
    }
}

template <int ACCUM>
__global__ __launch_bounds__(256, 4) void mlp_branch(
    const float* __restrict__ x,
    const float* __restrict__ W1, const float* __restrict__ b1, const float* __restrict__ a1,
    const float* __restrict__ W2, const float* __restrict__ b2, const float* __restrict__ a2,
    const float* __restrict__ W3, const float* __restrict__ b3, const float* __restrict__ a3,
    const float* __restrict__ W4, const float* __restrict__ b4,
    float* __restrict__ out, int n, float xscale)
{
    const int lane = threadIdx.x & 63;
    const int col  = lane & 15;
    const int g    = lane >> 4;
    const int wid  = (int)((blockIdx.x * blockDim.x + threadIdx.x) >> 6);
    const int nwaves = (int)((gridDim.x * blockDim.x) >> 6);
    const int ntiles = n >> 4;

    const bf8v z8 = {0, 0, 0, 0, 0, 0, 0, 0};

    // ---------------- preamble: fold params, build weight fragments --------
    // Layer 1 (VALU): q1[ch] = (a1*W1)[ch] * x + (a1*b1)[ch], ch = 16t+4g+j
    f4v w1p[4], b1p[4];
    #pragma unroll
    for (int t = 0; t < 4; ++t) {
        const int c0 = 16 * t + 4 * g;
        const f4v a1v = *(const f4v*)(a1 + c0);
        w1p[t] = a1v * *(const f4v*)(W1 + c0);
        b1p[t] = a1v * *(const f4v*)(b1 + c0);
    }

    // Layers 2,3 fragments: W'[o][k] = aout[o] * W[o][k] / ain[k]
    bf8v W2h[4][2], W2l[4][2], W3h[4][2], W3l[4][2];
    #pragma unroll
    for (int L = 0; L < 2; ++L) {
        const float* W    = L ? W3 : W2;
        const float* aout = L ? a3 : a2;
        const float* ain  = L ? a2 : a1;
        #pragma unroll
        for (int s = 0; s < 2; ++s) {
            const int kb = 32 * s + 4 * g;
            const f4v aia = *(const f4v*)(ain + kb);
            const f4v aib = *(const f4v*)(ain + kb + 16);
            float ra[8];
            #pragma unroll
            for (int j = 0; j < 4; ++j) { ra[j] = 1.0f / aia[j]; ra[4 + j] = 1.0f / aib[j]; }
            #pragma unroll
            for (int t = 0; t < 4; ++t) {
                const int o = 16 * t + col;
                const f4v wa = *(const f4v*)(W + o * 64 + kb);
                const f4v wb = *(const f4v*)(W + o * 64 + kb + 16);
                const float ao = aout[o];
                bf8v hh = z8, ll = z8;
                #pragma unroll
                for (int j = 0; j < 8; ++j) {
                    const float wv = (j < 4) ? wa[j & 3] : wb[j & 3];
                    const float wp = ao * wv * ra[j];
                    unsigned short hb = f2bf(wp);
                    hh[j] = (short)hb;
                    ll[j] = (short)f2bf(wp - bf2f(hb));
                }
                if (L == 0) { W2h[t][s] = hh; W2l[t][s] = ll; }
                else        { W3h[t][s] = hh; W3l[t][s] = ll; }
            }
        }
    }

    // scaled biases and w4' = w4 / a3 (per-lane quad = 16t + 4g + j)
    f4v bias2[4], bias3[4], w4p[4];
    #pragma unroll
    for (int t = 0; t < 4; ++t) {
        const int c0 = 16 * t + 4 * g;
        bias2[t] = *(const f4v*)(b2 + c0) * *(const f4v*)(a2 + c0);
        bias3[t] = *(const f4v*)(b3 + c0) * *(const f4v*)(a3 + c0);
        w4p[t]   = *(const f4v*)(W4 + c0) / *(const f4v*)(a3 + c0);
    }
    const float b4v = b4[0];

    // ---------------- main loop over 16-point tiles ------------------------
    int tile = wid;
    if (tile >= ntiles) return;
    float xc = xscale * x[tile * 16 + col];
    float oc = ACCUM ? out[tile * 16 + col] : 0.0f;

    while (tile < ntiles) {
        const int tnext = tile + nwaves;
        float xn = 0.0f, on = 0.0f;
        if (tnext < ntiles) {
            xn = xscale * x[tnext * 16 + col];
            if (ACCUM) on = out[tnext * 16 + col];
        }

        // ---- layer 1 (fp32 VALU) ----
        f4v acc[4];
        #pragma unroll
        for (int t = 0; t < 4; ++t) {
            #pragma unroll
            for (int j = 0; j < 4; ++j) acc[t][j] = fmaf(w1p[t][j], xc, b1p[t][j]);
        }
        bf8v Bh[2], Bl[2];
        act_and_frags(acc, Bh, Bl);    // g1 -> fragments

        // ---- layer 2 ----
        f4v acc2[4];
        #pragma unroll
        for (int t = 0; t < 4; ++t) {
            f4v d = bias2[t];
            #pragma unroll
            for (int s = 0; s < 2; ++s) {
                d = MFMA(W2h[t][s], Bh[s], d);
                d = MFMA(W2h[t][s], Bl[s], d);
                d = MFMA(W2l[t][s], Bh[s], d);
            }
            acc2[t] = d;
        }
        act_and_frags(acc2, Bh, Bl);   // g2 -> fragments

        // ---- layer 3 ----
        #pragma unroll
        for (int t = 0; t < 4; ++t) {
            f4v d = bias3[t];
            #pragma unroll
            for (int s = 0; s < 2; ++s) {
                d = MFMA(W3h[t][s], Bh[s], d);
                d = MFMA(W3h[t][s], Bl[s], d);
                d = MFMA(W3l[t][s], Bh[s], d);
            }
            acc[t] = d;
        }
        #pragma unroll
        for (int t = 0; t < 4; ++t) {
            #pragma unroll
            for (int j = 0; j < 4; ++j) {
                float q = acc[t][j];
                float s = __sinf(q);
                acc[t][j] = fmaf(s, s, q);
            }
        }

        // ---- layer 4 ----
        float p = 0.0f;
        #pragma unroll
        for (int t = 0; t < 4; ++t) {
            #pragma unroll
            for (int j = 0; j < 4; ++j) p = fmaf(w4p[t][j], acc[t][j], p);
        }
        p += __shfl_xor(p, 16);
        p += __shfl_xor(p, 32);

        const float res = p + b4v + oc;
        if (lane < 16) out[tile * 16 + col] = res;

        tile = tnext; xc = xn; oc = on;
    }
}

extern "C" void kernel_launch(void* const* d_in, const int* in_sizes, int n_in,
                              void* d_out, int out_size, void* d_ws, size_t ws_size,
                              hipStream_t stream) {
    const float* x   = (const float*)d_in[0];
    const float* W1a = (const float*)d_in[1];
    const float* b1a = (const float*)d_in[2];
    const float* a1a = (const float*)d_in[3];
    const float* W2a = (const float*)d_in[4];
    const float* b2a = (const float*)d_in[5];
    const float* a2a = (const float*)d_in[6];
    const float* W3a = (const float*)d_in[7];
    const float* b3a = (const float*)d_in[8];
    const float* a3a = (const float*)d_in[9];
    const float* W4a = (const float*)d_in[10];
    const float* b4a = (const float*)d_in[11];
    const float* W1b = (const float*)d_in[12];
    const float* b1b = (const float*)d_in[13];
    const float* a1b = (const float*)d_in[14];
    const float* W2b = (const float*)d_in[15];
    const float* b2b = (const float*)d_in[16];
    const float* a2b = (const float*)d_in[17];
    const float* W3b = (const float*)d_in[18];
    const float* b3b = (const float*)d_in[19];
    const float* a3b = (const float*)d_in[20];
    const float* W4b = (const float*)d_in[21];
    const float* b4b = (const float*)d_in[22];

    const int n = in_sizes[0];
    float* out = (float*)d_out;

    mlp_branch<0><<<1024, 256, 0, stream>>>(x, W1a, b1a, a1a, W2a, b2a, a2a,
                                            W3a, b3a, a3a, W4a, b4a,
                                            out, n, 1.0f);
    mlp_branch<1><<<1024, 256, 0, stream>>>(x, W1b, b1b, a1b, W2b, b2b, a2b,
                                            W3b, b3b, a3b, W4b, b4b,
                                            out, n, 2.0f);
}

// Round 6
// 340.839 us; speedup vs baseline: 4.0135x; 4.0135x over previous
//
#include <hip/hip_runtime.h>

// DoubleSin via bf16 MFMA (16x16x32), zero-LDS.
// Round-6 = round-4 kernel (128 VGPR, no spills) + grid 1024.
// Round-5 lesson: __launch_bounds__(256,4) forced a 64-VGPR clamp -> massive
// scratch spills (FETCH 2 GB, 2x slower). (256,2) is a MINIMUM of 2 waves/EU;
// the compiler picks 128 VGPR naturally and HW can still run 4 waves/SIMD,
// which grid=1024 (4096 waves) now fills.
// Structure: D = W'.H (weights as A-operand); D registers of layer L are
// exactly the B fragment of layer L+1 (no cross-lane traffic). Snake scales
// folded into weights: W_L' = diag(a_L) W_L diag(1/a_{L-1}); activation is
// param-free g(q) = q + sin^2(q). 3-term bf16 split Wh*Bh + Wh*Bl + Wl*Bh.

typedef __attribute__((ext_vector_type(8))) short bf8v;
typedef __attribute__((ext_vector_type(4))) float f4v;

union BF8U { bf8v v; unsigned d[4]; unsigned short s[8]; };

__device__ __forceinline__ unsigned short f2bf(float f) {   // preamble only
    unsigned u = __builtin_bit_cast(unsigned, f);
    u += 0x7fffu + ((u >> 16) & 1u);
    return (unsigned short)(u >> 16);
}
__device__ __forceinline__ float bf2f(unsigned short b) {
    return __builtin_bit_cast(float, (unsigned)b << 16);
}
__device__ __forceinline__ unsigned cvt_pk_bf16(float lo, float hi) {
    unsigned r;
    asm("v_cvt_pk_bf16_f32 %0, %1, %2" : "=v"(r) : "v"(lo), "v"(hi));
    return r;
}

#define MFMA(a, b, c) __builtin_amdgcn_mfma_f32_16x16x32_bf16((a), (b), (c), 0, 0, 0)

// g(q) = q + sin^2 q on all 16 accs, then build hi/lo B fragments via cvt_pk
__device__ __forceinline__ void act_and_frags(f4v (&acc)[4], bf8v (&Bh)[2], bf8v (&Bl)[2]) {
    #pragma unroll
    for (int t = 0; t < 4; ++t) {
        #pragma unroll
        for (int j = 0; j < 4; ++j) {
            float q = acc[t][j];
            float s = __sinf(q);
            acc[t][j] = fmaf(s, s, q);
        }
    }
    #pragma unroll
    for (int s2 = 0; s2 < 2; ++s2) {
        BF8U h, l;
        #pragma unroll
        for (int p = 0; p < 4; ++p) {
            const int t = 2 * s2 + (p >> 1);
            const int j0 = (p & 1) * 2;
            const float v0 = acc[t][j0], v1 = acc[t][j0 + 1];
            const unsigned hd = cvt_pk_bf16(v0, v1);      // lo16=bf(v0), hi16=bf(v1)
            h.d[p] = hd;
            const float r0 = v0 - __builtin_bit_cast(float, hd << 16);
            const float r1 = v1 - __builtin_bit_cast(float, hd & 0xffff0000u);
            l.d[p] = cvt_pk_bf16(r0, r1);
        }
        Bh[s2] = h.v; Bl[s2] = l.v;
    }
}

template <int ACCUM>
__global__ __launch_bounds__(256, 2) void mlp_branch(
    const float* __restrict__ x,
    const float* __restrict__ W1, const float* __restrict__ b1, const float* __restrict__ a1,
    const float* __restrict__ W2, const float* __restrict__ b2, const float* __restrict__ a2,
    const float* __restrict__ W3, const float* __restrict__ b3, const float* __restrict__ a3,
    const float* __restrict__ W4, const float* __restrict__ b4,
    float* __restrict__ out, int n, float xscale)
{
    const int lane = threadIdx.x & 63;
    const int col  = lane & 15;
    const int g    = lane >> 4;
    const int wid  = (int)((blockIdx.x * blockDim.x + threadIdx.x) >> 6);
    const int nwaves = (int)((gridDim.x * blockDim.x) >> 6);
    const int ntiles = n >> 4;

    const bf8v z8 = {0, 0, 0, 0, 0, 0, 0, 0};

    // ---------------- preamble: fold params, build weight fragments --------
    // Layer 1 (VALU): q1[ch] = (a1*W1)[ch] * x + (a1*b1)[ch], ch = 16t+4g+j
    f4v w1p[4], b1p[4];
    #pragma unroll
    for (int t = 0; t < 4; ++t) {
        const int c0 = 16 * t + 4 * g;
        const f4v a1v = *(const f4v*)(a1 + c0);
        w1p[t] = a1v * *(const f4v*)(W1 + c0);
        b1p[t] = a1v * *(const f4v*)(b1 + c0);
    }

    // Layers 2,3 fragments: W'[o][k] = aout[o] * W[o][k] / ain[k]
    bf8v W2h[4][2], W2l[4][2], W3h[4][2], W3l[4][2];
    #pragma unroll
    for (int L = 0; L < 2; ++L) {
        const float* W    = L ? W3 : W2;
        const float* aout = L ? a3 : a2;
        const float* ain  = L ? a2 : a1;
        #pragma unroll
        for (int s = 0; s < 2; ++s) {
            const int kb = 32 * s + 4 * g;
            const f4v aia = *(const f4v*)(ain + kb);
            const f4v aib = *(const f4v*)(ain + kb + 16);
            float ra[8];
            #pragma unroll
            for (int j = 0; j < 4; ++j) { ra[j] = 1.0f / aia[j]; ra[4 + j] = 1.0f / aib[j]; }
            #pragma unroll
            for (int t = 0; t < 4; ++t) {
                const int o = 16 * t + col;
                const f4v wa = *(const f4v*)(W + o * 64 + kb);
                const f4v wb = *(const f4v*)(W + o * 64 + kb + 16);
                const float ao = aout[o];
                bf8v hh = z8, ll = z8;
                #pragma unroll
                for (int j = 0; j < 8; ++j) {
                    const float wv = (j < 4) ? wa[j & 3] : wb[j & 3];
                    const float wp = ao * wv * ra[j];
                    unsigned short hb = f2bf(wp);
                    hh[j] = (short)hb;
                    ll[j] = (short)f2bf(wp - bf2f(hb));
                }
                if (L == 0) { W2h[t][s] = hh; W2l[t][s] = ll; }
                else        { W3h[t][s] = hh; W3l[t][s] = ll; }
            }
        }
    }

    // scaled biases and w4' = w4 / a3 (per-lane quad = 16t + 4g + j)
    f4v bias2[4], bias3[4], w4p[4];
    #pragma unroll
    for (int t = 0; t < 4; ++t) {
        const int c0 = 16 * t + 4 * g;
        bias2[t] = *(const f4v*)(b2 + c0) * *(const f4v*)(a2 + c0);
        bias3[t] = *(const f4v*)(b3 + c0) * *(const f4v*)(a3 + c0);
        w4p[t]   = *(const f4v*)(W4 + c0) / *(const f4v*)(a3 + c0);
    }
    const float b4v = b4[0];

    // ---------------- main loop over 16-point tiles ------------------------
    int tile = wid;
    if (tile >= ntiles) return;
    float xc = xscale * x[tile * 16 + col];
    float oc = ACCUM ? out[tile * 16 + col] : 0.0f;

    while (tile < ntiles) {
        const int tnext = tile + nwaves;
        float xn = 0.0f, on = 0.0f;
        if (tnext < ntiles) {
            xn = xscale * x[tnext * 16 + col];
            if (ACCUM) on = out[tnext * 16 + col];
        }

        // ---- layer 1 (fp32 VALU) ----
        f4v acc[4];
        #pragma unroll
        for (int t = 0; t < 4; ++t) {
            #pragma unroll
            for (int j = 0; j < 4; ++j) acc[t][j] = fmaf(w1p[t][j], xc, b1p[t][j]);
        }
        bf8v Bh[2], Bl[2];
        act_and_frags(acc, Bh, Bl);    // g1 -> fragments

        // ---- layer 2 ----
        f4v acc2[4];
        #pragma unroll
        for (int t = 0; t < 4; ++t) {
            f4v d = bias2[t];
            #pragma unroll
            for (int s = 0; s < 2; ++s) {
                d = MFMA(W2h[t][s], Bh[s], d);
                d = MFMA(W2h[t][s], Bl[s], d);
                d = MFMA(W2l[t][s], Bh[s], d);
            }
            acc2[t] = d;
        }
        act_and_frags(acc2, Bh, Bl);   // g2 -> fragments

        // ---- layer 3 ----
        #pragma unroll
        for (int t = 0; t < 4; ++t) {
            f4v d = bias3[t];
            #pragma unroll
            for (int s = 0; s < 2; ++s) {
                d = MFMA(W3h[t][s], Bh[s], d);
                d = MFMA(W3h[t][s], Bl[s], d);
                d = MFMA(W3l[t][s], Bh[s], d);
            }
            acc[t] = d;
        }
        #pragma unroll
        for (int t = 0; t < 4; ++t) {
            #pragma unroll
            for (int j = 0; j < 4; ++j) {
                float q = acc[t][j];
                float s = __sinf(q);
                acc[t][j] = fmaf(s, s, q);
            }
        }

        // ---- layer 4 ----
        float p = 0.0f;
        #pragma unroll
        for (int t = 0; t < 4; ++t) {
            #pragma unroll
            for (int j = 0; j < 4; ++j) p = fmaf(w4p[t][j], acc[t][j], p);
        }
        p += __shfl_xor(p, 16);
        p += __shfl_xor(p, 32);

        const float res = p + b4v + oc;
        if (lane < 16) out[tile * 16 + col] = res;

        tile = tnext; xc = xn; oc = on;
    }
}

extern "C" void kernel_launch(void* const* d_in, const int* in_sizes, int n_in,
                              void* d_out, int out_size, void* d_ws, size_t ws_size,
                              hipStream_t stream) {
    const float* x   = (const float*)d_in[0];
    const float* W1a = (const float*)d_in[1];
    const float* b1a = (const float*)d_in[2];
    const float* a1a = (const float*)d_in[3];
    const float* W2a = (const float*)d_in[4];
    const float* b2a = (const float*)d_in[5];
    const float* a2a = (const float*)d_in[6];
    const float* W3a = (const float*)d_in[7];
    const float* b3a = (const float*)d_in[8];
    const float* a3a = (const float*)d_in[9];
    const float* W4a = (const float*)d_in[10];
    const float* b4a = (const float*)d_in[11];
    const float* W1b = (const float*)d_in[12];
    const float* b1b = (const float*)d_in[13];
    const float* a1b = (const float*)d_in[14];
    const float* W2b = (const float*)d_in[15];
    const float* b2b = (const float*)d_in[16];
    const float* a2b = (const float*)d_in[17];
    const float* W3b = (const float*)d_in[18];
    const float* b3b = (const float*)d_in[19];
    const float* a3b = (const float*)d_in[20];
    const float* W4b = (const float*)d_in[21];
    const float* b4b = (const float*)d_in[22];

    const int n = in_sizes[0];
    float* out = (float*)d_out;

    mlp_branch<0><<<1024, 256, 0, stream>>>(x, W1a, b1a, a1a, W2a, b2a, a2a,
                                            W3a, b3a, a3a, W4a, b4a,
                                            out, n, 1.0f);
    mlp_branch<1><<<1024, 256, 0, stream>>>(x, W1b, b1b, a1b, W2b, b2b, a2b,
                                            W3b, b3b, a3b, W4b, b4b,
                                            out, n, 2.0f);
}